// Round 1
// baseline (46.468 us; speedup 1.0000x reference)
//
#include <hip/hip_runtime.h>
#include <hip/hip_bf16.h>

typedef short bf16x8 __attribute__((ext_vector_type(8)));
typedef float f32x4 __attribute__((ext_vector_type(4)));

#define LG2G (-0.04580369f)          /* log2(0.96875) */
#define BATCH 4
#define SEQ 4096
#define DIM 64

__device__ __forceinline__ ushort f2bf(float x){
  union { float f; unsigned u; } v; v.f = x;
  unsigned r = v.u + 0x7fffu + ((v.u >> 16) & 1u);
  return (ushort)(r >> 16);
}

// ---- kernel 1: xpos rotation + scale, fp32 -> bf16 q,k ----
__global__ __launch_bounds__(256) void xpos_prep(const float* __restrict__ Q,
                                                 const float* __restrict__ K,
                                                 ushort* __restrict__ qb,
                                                 ushort* __restrict__ kb){
  int tid = blockIdx.x * 256 + threadIdx.x;   // B*S*32 pairs
  int i = tid & 31;                            // pair index (d/2)
  int row = tid >> 5;                          // b*4096 + s
  int s = row & (SEQ - 1);
  float fs = (float)s;
  float base = ((float)(2 * i) + 25.6f) * (1.0f / 89.6f);
  float sc = exp2f(log2f(base) * (fs * (1.0f / 512.0f)));
  float invf = exp2f((float)i * -0.4152410118609203f);  // 10000^(-i/32)
  float ang = fs * invf;
  float sn = sinf(ang), cs = cosf(ang);

  float2 qv = ((const float2*)Q)[tid];
  float2 kv = ((const float2*)K)[tid];

  float ssq = sn * sc, csq = cs * sc;
  float isc = 1.0f / sc;
  float ssk = sn * isc, csk = cs * isc;

  unsigned q01 = (unsigned)f2bf(qv.x * csq - qv.y * ssq) |
                 ((unsigned)f2bf(qv.y * csq + qv.x * ssq) << 16);
  unsigned k01 = (unsigned)f2bf(kv.x * csk - kv.y * ssk) |
                 ((unsigned)f2bf(kv.y * csk + kv.x * ssk) << 16);
  ((unsigned*)qb)[tid] = q01;
  ((unsigned*)kb)[tid] = k01;
}

// ---- kernel 2: V fp32 [b][s][64] -> bf16 V^T [b][v][s] ----
__global__ __launch_bounds__(256) void vtrans(const float* __restrict__ V,
                                              ushort* __restrict__ vt){
  __shared__ ushort tile[64][65];
  int bs = blockIdx.x;                  // 0..255 : b*64 + s-tile
  int b = bs >> 6, st = bs & 63;
  int s0 = st * 64;
  int t = threadIdx.x;
  int v = t & 63, sl = t >> 6;
  #pragma unroll
  for (int it = 0; it < 16; ++it){
    int s = sl + it * 4;
    tile[s][v] = f2bf(V[((size_t)(b * SEQ + s0 + s)) * 64 + v]);
  }
  __syncthreads();
  int s2 = t & 63, vq = t >> 6;
  #pragma unroll
  for (int it = 0; it < 16; ++it){
    int v2 = vq + it * 4;
    vt[((size_t)(b * 64 + v2)) * SEQ + s0 + s2] = tile[s2][v2];
  }
}

// ---- kernel 3: banded flash retention ----
// grid 256 = b(4) x btile(64); block 512 = 8 waves.
// wave = (h, j): strip rows [btile*64 + j*16, +16), m-tile parity h.
__global__ __launch_bounds__(512) void retention(const ushort* __restrict__ qb,
                                                 const ushort* __restrict__ kb,
                                                 const ushort* __restrict__ vt,
                                                 float* __restrict__ out){
  __shared__ ushort Pbuf[8][16][72];    // per-wave P strip, padded rows
  __shared__ float  Obuf[4][16][65];    // half-combine buffers

  int bx = blockIdx.x;
  int b = bx >> 6, btile = bx & 63;
  int tid = threadIdx.x;
  int wave = tid >> 6, lane = tid & 63;
  int h = wave >> 2, j = wave & 3;
  int g = lane >> 4, c = lane & 15;
  int r0 = btile * 64 + j * 16;                 // strip row within batch
  size_t rowbase = (size_t)b * SEQ + r0;
  int t0 = btile >= 16 ? btile - 16 : 0;        // decay cutoff ~1024
  int t1 = btile;

  // q A-fragments (row = c, k = kk*32 + g*8 + [0..7])
  const ushort* qrow = qb + (rowbase + c) * 64 + g * 8;
  bf16x8 aq0 = *(const bf16x8*)(qrow);
  bf16x8 aq1 = *(const bf16x8*)(qrow + 32);

  float rowpow[4], colpow[4];
  #pragma unroll
  for (int r = 0; r < 4; ++r) rowpow[r] = exp2f((float)(g * 4 + r) * LG2G);
  #pragma unroll
  for (int nb = 0; nb < 4; ++nb) colpow[nb] = exp2f((float)(-(nb * 16 + c)) * LG2G);

  f32x4 acc_o[4];
  #pragma unroll
  for (int vb = 0; vb < 4; ++vb) acc_o[vb] = (f32x4)0.0f;

  for (int t = t0 + h; t <= t1; t += 2){
    int m0 = t * 64;
    float tilepow = exp2f((float)(r0 - m0) * LG2G);

    // S = q k^T  (A=q strip 16xK, B=k rows as cols)
    const ushort* kbase = kb + ((size_t)b * SEQ + m0 + c) * 64 + g * 8;
    f32x4 sacc[4];
    #pragma unroll
    for (int nb = 0; nb < 4; ++nb){
      sacc[nb] = (f32x4)0.0f;
      bf16x8 bk0 = *(const bf16x8*)(kbase + (size_t)nb * 16 * 64);
      bf16x8 bk1 = *(const bf16x8*)(kbase + (size_t)nb * 16 * 64 + 32);
      sacc[nb] = __builtin_amdgcn_mfma_f32_16x16x32_bf16(aq0, bk0, sacc[nb], 0, 0, 0);
      sacc[nb] = __builtin_amdgcn_mfma_f32_16x16x32_bf16(aq1, bk1, sacc[nb], 0, 0, 0);
    }

    // decay + causal mask, write P strip to LDS (bf16)
    #pragma unroll
    for (int nb = 0; nb < 4; ++nb){
      float cp = tilepow * colpow[nb];
      #pragma unroll
      for (int r = 0; r < 4; ++r){
        int diff = (r0 + g * 4 + r) - (m0 + nb * 16 + c);
        float p = (diff >= 0) ? sacc[nb][r] * (rowpow[r] * cp) : 0.0f;
        Pbuf[wave][g * 4 + r][nb * 16 + c] = f2bf(p);
      }
    }

    // P A-fragments back from LDS (row = c, k = kk*32 + g*8 + [0..7])
    bf16x8 ap0 = *(const bf16x8*)(&Pbuf[wave][c][g * 8]);
    bf16x8 ap1 = *(const bf16x8*)(&Pbuf[wave][c][32 + g * 8]);

    // O += P * V   (B from V^T: col = v = vb*16+c, k = m contiguous)
    const ushort* vbase = vt + ((size_t)b * 64 + c) * SEQ + m0 + g * 8;
    #pragma unroll
    for (int vb = 0; vb < 4; ++vb){
      bf16x8 bv0 = *(const bf16x8*)(vbase + (size_t)vb * 16 * SEQ);
      bf16x8 bv1 = *(const bf16x8*)(vbase + (size_t)vb * 16 * SEQ + 32);
      acc_o[vb] = __builtin_amdgcn_mfma_f32_16x16x32_bf16(ap0, bv0, acc_o[vb], 0, 0, 0);
      acc_o[vb] = __builtin_amdgcn_mfma_f32_16x16x32_bf16(ap1, bv1, acc_o[vb], 0, 0, 0);
    }
  }

  // combine the two m-halves (waves j and j+4), then store
  if (h == 1){
    #pragma unroll
    for (int vb = 0; vb < 4; ++vb)
      #pragma unroll
      for (int r = 0; r < 4; ++r)
        Obuf[j][g * 4 + r][vb * 16 + c] = acc_o[vb][r];
  }
  __syncthreads();
  if (h == 0){
    #pragma unroll
    for (int vb = 0; vb < 4; ++vb)
      #pragma unroll
      for (int r = 0; r < 4; ++r){
        float val = acc_o[vb][r] + Obuf[j][g * 4 + r][vb * 16 + c];
        out[(rowbase + g * 4 + r) * 64 + vb * 16 + c] = val;
      }
  }
}

extern "C" void kernel_launch(void* const* d_in, const int* in_sizes, int n_in,
                              void* d_out, int out_size, void* d_ws, size_t ws_size,
                              hipStream_t stream){
  (void)in_sizes; (void)n_in; (void)out_size; (void)ws_size;
  const float* Q = (const float*)d_in[0];
  const float* K = (const float*)d_in[1];
  const float* V = (const float*)d_in[2];
  float* out = (float*)d_out;

  ushort* qb = (ushort*)d_ws;                       // 2 MB
  ushort* kb = qb + (size_t)BATCH * SEQ * DIM;      // 2 MB
  ushort* vt = kb + (size_t)BATCH * SEQ * DIM;      // 2 MB

  hipLaunchKernelGGL(xpos_prep, dim3(BATCH * SEQ * 32 / 256), dim3(256), 0, stream, Q, K, qb, kb);
  hipLaunchKernelGGL(vtrans, dim3(BATCH * 64), dim3(256), 0, stream, V, vt);
  hipLaunchKernelGGL(retention, dim3(BATCH * 64), dim3(512), 0, stream, qb, kb, vt, out);
}

// Round 2
// 31.189 us; speedup vs baseline: 1.4899x; 1.4899x over previous
//
#include <hip/hip_runtime.h>
#include <hip/hip_bf16.h>

typedef short bf16x8 __attribute__((ext_vector_type(8)));
typedef float f32x4 __attribute__((ext_vector_type(4)));

#define LG2G (-0.04580369f)          /* log2(0.96875) */
#define BATCH 4
#define SEQ 4096
#define DIM 64
#define BAND 8                       /* m-tiles of 64 kept before the diagonal */

__device__ __forceinline__ ushort f2bf(float x){
  union { float f; unsigned u; } v; v.f = x;
  unsigned r = v.u + 0x7fffu + ((v.u >> 16) & 1u);
  return (ushort)(r >> 16);
}

// ---- kernel 1: fused prep ----
// blocks [0,2048): xpos rotation+scale fp32->bf16 q,k
// blocks [2048,2304): V fp32 [b][s][64] -> bf16 V^T [b][v][s]
__global__ __launch_bounds__(256) void prep(const float* __restrict__ Q,
                                            const float* __restrict__ K,
                                            const float* __restrict__ V,
                                            ushort* __restrict__ qb,
                                            ushort* __restrict__ kb,
                                            ushort* __restrict__ vt){
  __shared__ ushort tile[64][65];
  int bx = blockIdx.x;
  if (bx < 2048){
    int tid = bx * 256 + threadIdx.x;           // B*S*32 pairs
    int i = tid & 31;                            // pair index (d/2)
    int row = tid >> 5;                          // b*4096 + s
    int s = row & (SEQ - 1);
    float fs = (float)s;
    float base = ((float)(2 * i) + 25.6f) * (1.0f / 89.6f);
    float sc = exp2f(log2f(base) * (fs * (1.0f / 512.0f)));
    float invf = exp2f((float)i * -0.4152410118609203f);  // 10000^(-i/32)
    float ang = fs * invf;
    float sn = sinf(ang), cs = cosf(ang);

    float2 qv = ((const float2*)Q)[tid];
    float2 kv = ((const float2*)K)[tid];

    float ssq = sn * sc, csq = cs * sc;
    float isc = 1.0f / sc;
    float ssk = sn * isc, csk = cs * isc;

    unsigned q01 = (unsigned)f2bf(qv.x * csq - qv.y * ssq) |
                   ((unsigned)f2bf(qv.y * csq + qv.x * ssq) << 16);
    unsigned k01 = (unsigned)f2bf(kv.x * csk - kv.y * ssk) |
                   ((unsigned)f2bf(kv.y * csk + kv.x * ssk) << 16);
    ((unsigned*)qb)[tid] = q01;
    ((unsigned*)kb)[tid] = k01;
  } else {
    int bs = bx - 2048;                   // 0..255 : b*64 + s-tile
    int b = bs >> 6, st = bs & 63;
    int s0 = st * 64;
    int t = threadIdx.x;
    int v = t & 63, sl = t >> 6;
    #pragma unroll
    for (int it = 0; it < 16; ++it){
      int s = sl + it * 4;
      tile[s][v] = f2bf(V[((size_t)(b * SEQ + s0 + s)) * 64 + v]);
    }
    __syncthreads();
    int s2 = t & 63, vq = t >> 6;
    #pragma unroll
    for (int it = 0; it < 16; ++it){
      int v2 = vq + it * 4;
      vt[((size_t)(b * 64 + v2)) * SEQ + s0 + s2] = tile[s2][v2];
    }
  }
}

// ---- kernel 2: banded flash retention (swapped-QK^T form) ----
// grid 256 = b(4) x btile(64); block 512 = 8 waves.
// wave = (h, j): strip rows [btile*64 + j*16, +16), m-tile parity h.
// S^T trick: sacc = mfma(k_frag, q_frag) -> lane (g,c) holds S[q row c][m = nb*16+g*4+r],
// so the 4 regs of each nb are CONTIGUOUS in m -> cvt_pk + ds_write_b64.
__global__ __launch_bounds__(512) void retention(const ushort* __restrict__ qb,
                                                 const ushort* __restrict__ kb,
                                                 const ushort* __restrict__ vt,
                                                 float* __restrict__ out){
  __shared__ ushort Pbuf[8][16][72];    // per-wave P strip [qrow][m], padded
  __shared__ float  Obuf[4][16][65];    // half-combine buffers

  int bx = blockIdx.x;
  int b = bx >> 6, btile = bx & 63;
  int tid = threadIdx.x;
  int wave = tid >> 6, lane = tid & 63;
  int h = wave >> 2, j = wave & 3;
  int g = lane >> 4, c = lane & 15;
  int r0 = btile * 64 + j * 16;                 // strip row within batch
  size_t rowbase = (size_t)b * SEQ + r0;
  int t0 = btile >= BAND ? btile - BAND : 0;    // decay cutoff 512
  int t1 = btile;

  // q fragments (row = c, k = kk*32 + g*8 + [0..7]) - used as B operand
  const ushort* qrow = qb + (rowbase + c) * 64 + g * 8;
  bf16x8 bq0 = *(const bf16x8*)(qrow);
  bf16x8 bq1 = *(const bf16x8*)(qrow + 32);

  // col-decay gamma^{-(nb*16+g*4+r)}, hoisted (max gamma^-63 = 7.4, safe)
  float cpw[4][4];
  #pragma unroll
  for (int nb = 0; nb < 4; ++nb)
    #pragma unroll
    for (int r = 0; r < 4; ++r)
      cpw[nb][r] = exp2f((float)(-(nb * 16 + g * 4 + r)) * LG2G);

  f32x4 acc_o[4];
  #pragma unroll
  for (int vb = 0; vb < 4; ++vb) acc_o[vb] = (f32x4)0.0f;

  for (int t = t0 + h; t <= t1; t += 2){
    int m0 = t * 64;

    // S^T = mfma(k, q): lane (g,c) gets S[c][m0 + nb*16 + g*4 + r]
    const ushort* kbase = kb + ((size_t)b * SEQ + m0 + c) * 64 + g * 8;
    f32x4 st[4];
    #pragma unroll
    for (int nb = 0; nb < 4; ++nb){
      bf16x8 ak0 = *(const bf16x8*)(kbase + (size_t)nb * 16 * 64);
      bf16x8 ak1 = *(const bf16x8*)(kbase + (size_t)nb * 16 * 64 + 32);
      st[nb] = (f32x4)0.0f;
      st[nb] = __builtin_amdgcn_mfma_f32_16x16x32_bf16(ak0, bq0, st[nb], 0, 0, 0);
      st[nb] = __builtin_amdgcn_mfma_f32_16x16x32_bf16(ak1, bq1, st[nb], 0, 0, 0);
    }

    // decay: gamma^{(r0+c) - m0} per-lane scalar x hoisted col powers
    int drow = r0 + c - m0;
    float rowfac = exp2f((float)drow * LG2G);
    float p[4][4];
    #pragma unroll
    for (int nb = 0; nb < 4; ++nb)
      #pragma unroll
      for (int r = 0; r < 4; ++r)
        p[nb][r] = st[nb][r] * (rowfac * cpw[nb][r]);

    if (t == t1){                    // causal mask needed on diagonal tile only
      #pragma unroll
      for (int nb = 0; nb < 4; ++nb)
        #pragma unroll
        for (int r = 0; r < 4; ++r)
          if (drow < nb * 16 + g * 4 + r) p[nb][r] = 0.0f;
    }

    // pack pairs (RNE) + vector LDS write: 4 x ds_write_b64 per tile
    #pragma unroll
    for (int nb = 0; nb < 4; ++nb){
      unsigned w0, w1;
      asm("v_cvt_pk_bf16_f32 %0, %1, %2" : "=v"(w0) : "v"(p[nb][0]), "v"(p[nb][1]));
      asm("v_cvt_pk_bf16_f32 %0, %1, %2" : "=v"(w1) : "v"(p[nb][2]), "v"(p[nb][3]));
      *(uint2*)&Pbuf[wave][c][nb * 16 + g * 4] = make_uint2(w0, w1);
    }

    // P A-fragments (row = c, k = kk*32 + g*8 + [0..7])
    bf16x8 ap0 = *(const bf16x8*)(&Pbuf[wave][c][g * 8]);
    bf16x8 ap1 = *(const bf16x8*)(&Pbuf[wave][c][32 + g * 8]);

    // O += P * V   (B from V^T: col = v = vb*16+c, k = m contiguous)
    const ushort* vbase = vt + ((size_t)b * 64 + c) * SEQ + m0 + g * 8;
    #pragma unroll
    for (int vb = 0; vb < 4; ++vb){
      bf16x8 bv0 = *(const bf16x8*)(vbase + (size_t)vb * 16 * SEQ);
      bf16x8 bv1 = *(const bf16x8*)(vbase + (size_t)vb * 16 * SEQ + 32);
      acc_o[vb] = __builtin_amdgcn_mfma_f32_16x16x32_bf16(ap0, bv0, acc_o[vb], 0, 0, 0);
      acc_o[vb] = __builtin_amdgcn_mfma_f32_16x16x32_bf16(ap1, bv1, acc_o[vb], 0, 0, 0);
    }
  }

  // combine the two m-halves (waves j and j+4), then store
  if (h == 1){
    #pragma unroll
    for (int vb = 0; vb < 4; ++vb)
      #pragma unroll
      for (int r = 0; r < 4; ++r)
        Obuf[j][g * 4 + r][vb * 16 + c] = acc_o[vb][r];
  }
  __syncthreads();
  if (h == 0){
    #pragma unroll
    for (int vb = 0; vb < 4; ++vb)
      #pragma unroll
      for (int r = 0; r < 4; ++r){
        float val = acc_o[vb][r] + Obuf[j][g * 4 + r][vb * 16 + c];
        out[(rowbase + g * 4 + r) * 64 + vb * 16 + c] = val;
      }
  }
}

extern "C" void kernel_launch(void* const* d_in, const int* in_sizes, int n_in,
                              void* d_out, int out_size, void* d_ws, size_t ws_size,
                              hipStream_t stream){
  (void)in_sizes; (void)n_in; (void)out_size; (void)ws_size;
  const float* Q = (const float*)d_in[0];
  const float* K = (const float*)d_in[1];
  const float* V = (const float*)d_in[2];
  float* out = (float*)d_out;

  ushort* qb = (ushort*)d_ws;                       // 2 MB
  ushort* kb = qb + (size_t)BATCH * SEQ * DIM;      // 2 MB
  ushort* vt = kb + (size_t)BATCH * SEQ * DIM;      // 2 MB

  hipLaunchKernelGGL(prep, dim3(2048 + 256), dim3(256), 0, stream, Q, K, V, qb, kb, vt);
  hipLaunchKernelGGL(retention, dim3(BATCH * 64), dim3(512), 0, stream, qb, kb, vt, out);
}

// Round 3
// 25.491 us; speedup vs baseline: 1.8229x; 1.2235x over previous
//
#include <hip/hip_runtime.h>
#include <hip/hip_bf16.h>

typedef short bf16x8 __attribute__((ext_vector_type(8)));
typedef float f32x4 __attribute__((ext_vector_type(4)));

#define LG2G (-0.045803689613125f)   /* log2(0.96875) */
#define BATCH 4
#define SEQ 4096
#define DIM 64
#define BAND 5                       /* m-tiles of 64 kept before the diagonal */

__device__ __forceinline__ ushort f2bf(float x){
  union { float f; unsigned u; } v; v.f = x;
  unsigned r = v.u + 0x7fffu + ((v.u >> 16) & 1u);
  return (ushort)(r >> 16);
}

// ---- kernel 1: fused prep ----
// blocks [0,1024): xpos rotation+scale fp32->bf16 q,k  (float4: 2 pairs/thread)
//   q rows additionally scaled by gamma^(s&63), k rows by gamma^-(s&63)
// blocks [1024,1280): V fp32 [b][s][64] -> bf16 V^T [b][v][s]
__global__ __launch_bounds__(256) void prep(const float* __restrict__ Q,
                                            const float* __restrict__ K,
                                            const float* __restrict__ V,
                                            ushort* __restrict__ qb,
                                            ushort* __restrict__ kb,
                                            ushort* __restrict__ vt){
  __shared__ ushort tile[64][65];
  int bx = blockIdx.x;
  if (bx < 1024){
    int tid = bx * 256 + threadIdx.x;           // B*S*16 float4 chunks
    int row = tid >> 4;                          // b*4096 + s
    int pp = tid & 15;                           // float4 index within row
    int s = row & (SEQ - 1);
    float fs = (float)s;
    float qg = exp2f((float)(s & 63) * LG2G);    // gamma^(s&63)
    float kg = exp2f((float)(-(s & 63)) * LG2G); // gamma^-(s&63)

    float4 qv = ((const float4*)Q)[tid];
    float4 kv = ((const float4*)K)[tid];
    unsigned qo[2], ko[2];
    #pragma unroll
    for (int u = 0; u < 2; ++u){
      int i = pp * 2 + u;                        // pair index (d/2)
      float base = ((float)(2 * i) + 25.6f) * (1.0f / 89.6f);
      float sc = exp2f(log2f(base) * (fs * (1.0f / 512.0f)));
      float invf = exp2f((float)i * -0.4152410118609203f);  // 10000^(-i/32)
      float ang = fs * invf;
      float sn = sinf(ang), cs = cosf(ang);
      float x0 = u ? qv.z : qv.x, x1 = u ? qv.w : qv.y;
      float y0 = u ? kv.z : kv.x, y1 = u ? kv.w : kv.y;
      float ssq = sn * sc * qg, csq = cs * sc * qg;
      float isc = kg / sc;
      float ssk = sn * isc, csk = cs * isc;
      qo[u] = (unsigned)f2bf(x0 * csq - x1 * ssq) |
              ((unsigned)f2bf(x1 * csq + x0 * ssq) << 16);
      ko[u] = (unsigned)f2bf(y0 * csk - y1 * ssk) |
              ((unsigned)f2bf(y1 * csk + y0 * ssk) << 16);
    }
    ((uint2*)qb)[tid] = make_uint2(qo[0], qo[1]);
    ((uint2*)kb)[tid] = make_uint2(ko[0], ko[1]);
  } else {
    int bs = bx - 1024;                   // 0..255 : b*64 + s-tile
    int b = bs >> 6, st = bs & 63;
    int s0 = st * 64;
    int t = threadIdx.x;
    int v = t & 63, sl = t >> 6;
    #pragma unroll
    for (int it = 0; it < 16; ++it){
      int s = sl + it * 4;
      tile[s][v] = f2bf(V[((size_t)(b * SEQ + s0 + s)) * 64 + v]);
    }
    __syncthreads();
    int s2 = t & 63, vq = t >> 6;
    #pragma unroll
    for (int it = 0; it < 16; ++it){
      int v2 = vq + it * 4;
      vt[((size_t)(b * 64 + v2)) * SEQ + s0 + s2] = tile[s2][v2];
    }
  }
}

// ---- kernel 2: banded flash retention (swapped-QK^T, operand-folded decay) ----
// grid 512 = b(4) x btile(64) x half(2); block 512 = 8 waves.
// wave = (h, j): strip rows [btile*64 + half*32 + j*16, +16), m-tile class h in 0..3.
// Decay: q,k pre-scaled by gamma^(+/-(row&63)) -> P = S'' * gamma^(64*(btile-t)),
// a wave-uniform running scalar. Causal mask only on the diagonal tile.
__global__ __launch_bounds__(512, 4) void retention(const ushort* __restrict__ qb,
                                                    const ushort* __restrict__ kb,
                                                    const ushort* __restrict__ vt,
                                                    float* __restrict__ out){
  __shared__ ushort Pbuf[8][16][72];     // per-wave P strip [qrow][m], padded
  __shared__ float  Obuf[2][3][16][65];  // partial-O combine buffers

  int bx = blockIdx.x;
  int b = bx >> 7;
  int rest = bx & 127;
  int btile = rest >> 1, half = rest & 1;
  int tid = threadIdx.x;
  int wave = tid >> 6, lane = tid & 63;
  int j = wave & 1, h = wave >> 1;
  int g = lane >> 4, c = lane & 15;
  int r0 = btile * 64 + half * 32 + j * 16;     // strip row within batch
  size_t rowbase = (size_t)b * SEQ + r0;
  int t0 = btile >= BAND ? btile - BAND : 0;    // decay cutoff 320
  int t1 = btile;

  // q fragments (row = c, k = kk*32 + g*8 + [0..7]) - used as B operand
  const ushort* qrow = qb + (rowbase + c) * 64 + g * 8;
  bf16x8 bq0 = *(const bf16x8*)(qrow);
  bf16x8 bq1 = *(const bf16x8*)(qrow + 32);

  f32x4 acc_o[4];
  #pragma unroll
  for (int vb = 0; vb < 4; ++vb) acc_o[vb] = (f32x4)0.0f;

  float tilefac = exp2f((float)(64 * (btile - t0 - h)) * LG2G);
  const float tstep = 3386.8804f;               // gamma^-256 (4-tile stride)

  for (int t = t0 + h; t <= t1; t += 4){
    int m0 = t * 64;

    // S''^T = mfma(k', q'): lane (g,c) gets S''[q row c][m0 + nb*16 + g*4 + r]
    const ushort* kbase = kb + ((size_t)b * SEQ + m0 + c) * 64 + g * 8;
    f32x4 st[4];
    #pragma unroll
    for (int nb = 0; nb < 4; ++nb){
      bf16x8 ak0 = *(const bf16x8*)(kbase + (size_t)nb * 1024);
      bf16x8 ak1 = *(const bf16x8*)(kbase + (size_t)nb * 1024 + 32);
      st[nb] = (f32x4)0.0f;
      st[nb] = __builtin_amdgcn_mfma_f32_16x16x32_bf16(ak0, bq0, st[nb], 0, 0, 0);
      st[nb] = __builtin_amdgcn_mfma_f32_16x16x32_bf16(ak1, bq1, st[nb], 0, 0, 0);
    }

    // P = S'' * tilefac (wave-uniform scalar); causal mask on diagonal tile only
    #pragma unroll
    for (int nb = 0; nb < 4; ++nb)
      #pragma unroll
      for (int r = 0; r < 4; ++r)
        st[nb][r] *= tilefac;
    if (t == t1){
      int drow = r0 + c - m0;
      #pragma unroll
      for (int nb = 0; nb < 4; ++nb)
        #pragma unroll
        for (int r = 0; r < 4; ++r)
          if (drow < nb * 16 + g * 4 + r) st[nb][r] = 0.0f;
    }

    // pack pairs (RNE) + vector LDS write: 4 x ds_write_b64 per tile
    #pragma unroll
    for (int nb = 0; nb < 4; ++nb){
      unsigned w0, w1;
      asm("v_cvt_pk_bf16_f32 %0, %1, %2" : "=v"(w0) : "v"(st[nb][0]), "v"(st[nb][1]));
      asm("v_cvt_pk_bf16_f32 %0, %1, %2" : "=v"(w1) : "v"(st[nb][2]), "v"(st[nb][3]));
      *(uint2*)&Pbuf[wave][c][nb * 16 + g * 4] = make_uint2(w0, w1);
    }

    // P A-fragments (row = c, k = kk*32 + g*8 + [0..7])
    bf16x8 ap0 = *(const bf16x8*)(&Pbuf[wave][c][g * 8]);
    bf16x8 ap1 = *(const bf16x8*)(&Pbuf[wave][c][32 + g * 8]);

    // O += P * V   (B from V^T: col = v = vb*16+c, k = m contiguous)
    const ushort* vbase = vt + ((size_t)b * 64 + c) * SEQ + m0 + g * 8;
    #pragma unroll
    for (int vb = 0; vb < 4; ++vb){
      bf16x8 bv0 = *(const bf16x8*)(vbase + (size_t)vb * 16 * SEQ);
      bf16x8 bv1 = *(const bf16x8*)(vbase + (size_t)vb * 16 * SEQ + 32);
      acc_o[vb] = __builtin_amdgcn_mfma_f32_16x16x32_bf16(ap0, bv0, acc_o[vb], 0, 0, 0);
      acc_o[vb] = __builtin_amdgcn_mfma_f32_16x16x32_bf16(ap1, bv1, acc_o[vb], 0, 0, 0);
    }

    tilefac *= tstep;
  }

  // combine the four m-classes (waves h=0..3 per strip j), then store
  if (h > 0){
    #pragma unroll
    for (int vb = 0; vb < 4; ++vb)
      #pragma unroll
      for (int r = 0; r < 4; ++r)
        Obuf[j][h - 1][g * 4 + r][vb * 16 + c] = acc_o[vb][r];
  }
  __syncthreads();
  if (h == 0){
    #pragma unroll
    for (int vb = 0; vb < 4; ++vb)
      #pragma unroll
      for (int r = 0; r < 4; ++r){
        float val = acc_o[vb][r]
                  + Obuf[j][0][g * 4 + r][vb * 16 + c]
                  + Obuf[j][1][g * 4 + r][vb * 16 + c]
                  + Obuf[j][2][g * 4 + r][vb * 16 + c];
        out[(rowbase + g * 4 + r) * 64 + vb * 16 + c] = val;
      }
  }
}

extern "C" void kernel_launch(void* const* d_in, const int* in_sizes, int n_in,
                              void* d_out, int out_size, void* d_ws, size_t ws_size,
                              hipStream_t stream){
  (void)in_sizes; (void)n_in; (void)out_size; (void)ws_size;
  const float* Q = (const float*)d_in[0];
  const float* K = (const float*)d_in[1];
  const float* V = (const float*)d_in[2];
  float* out = (float*)d_out;

  ushort* qb = (ushort*)d_ws;                       // 2 MB
  ushort* kb = qb + (size_t)BATCH * SEQ * DIM;      // 2 MB
  ushort* vt = kb + (size_t)BATCH * SEQ * DIM;      // 2 MB

  hipLaunchKernelGGL(prep, dim3(1024 + 256), dim3(256), 0, stream, Q, K, V, qb, kb, vt);
  hipLaunchKernelGGL(retention, dim3(BATCH * 128), dim3(512), 0, stream, qb, kb, vt, out);
}